// Round 1
// baseline (284.037 us; speedup 1.0000x reference)
//
#include <hip/hip_runtime.h>
#include <hip/hip_bf16.h>

// out[bt, i, d] = x[bt, i] * W[i, d] + b[i, d]
// B=64, P=2000, D=512, all float32.
// One thread per float4 of the output (D/4 = 128 per row).

#define P_DIM 2000
#define D4 128            // D/4
#define TOTAL4 (64 * P_DIM * D4)   // 16,384,000 float4 elements

__global__ __launch_bounds__(256) void FeatureExpander_49185965473877_kernel(
    const float* __restrict__ x,   // (B, P)
    const float4* __restrict__ W,  // (P, D/4)
    const float4* __restrict__ b,  // (P, D/4)
    float4* __restrict__ out)      // (B, P, D/4)
{
    int idx = blockIdx.x * blockDim.x + threadIdx.x;
    if (idx >= TOTAL4) return;

    int d4  = idx & (D4 - 1);      // D4 is power of two
    int row = idx >> 7;            // row = bt*P + i
    int bt  = row / P_DIM;         // magic-multiply div
    int i   = row - bt * P_DIM;

    float  xv = x[row];            // x is (B,P) row-major: x[bt*P+i] == x[row]
    float4 wv = W[i * D4 + d4];
    float4 bv = b[i * D4 + d4];

    float4 o;
    o.x = fmaf(xv, wv.x, bv.x);
    o.y = fmaf(xv, wv.y, bv.y);
    o.z = fmaf(xv, wv.z, bv.z);
    o.w = fmaf(xv, wv.w, bv.w);
    out[idx] = o;

    (void)bt;
}

extern "C" void kernel_launch(void* const* d_in, const int* in_sizes, int n_in,
                              void* d_out, int out_size, void* d_ws, size_t ws_size,
                              hipStream_t stream) {
    const float*  x = (const float*)d_in[0];
    const float4* W = (const float4*)d_in[1];
    const float4* b = (const float4*)d_in[2];
    float4* out = (float4*)d_out;

    const int threads = 256;
    const int blocks  = (TOTAL4 + threads - 1) / threads;  // 64000
    FeatureExpander_49185965473877_kernel<<<blocks, threads, 0, stream>>>(x, W, b, out);
}

// Round 3
// 267.328 us; speedup vs baseline: 1.0625x; 1.0625x over previous
//
#include <hip/hip_runtime.h>
#include <hip/hip_bf16.h>

// out[bt, i, d] = x[bt, i] * W[i, d] + b[i, d]
// B=64, P=2000, D=512, all float32.
//
// R3 = R2 with the nontemporal-store type fixed: clang's
// __builtin_nontemporal_store requires a native vector type, not HIP's
// float4 struct. Use ext_vector_type(4) float.
//
// Structure: one thread per (bt_chunk, i, d4). W/b fragments load ONCE into
// registers and serve BT_CHUNK=16 bt values -> read traffic ~34MB compulsory
// instead of 64 cache-thrashed 8MB sweeps. Output stored nontemporally
// (write-once stream, never re-read; keeps W/b lines resident in L2/L3).

typedef float fx4 __attribute__((ext_vector_type(4)));

#define B_DIM 64
#define P_DIM 2000
#define D4 128                 // D/4 float4s per row
#define BT_CHUNK 16
#define N_CHUNK (B_DIM / BT_CHUNK)            // 4
#define N_THREADS (N_CHUNK * P_DIM * D4)      // 1,024,000

__global__ __launch_bounds__(256) void FeatureExpander_49185965473877_kernel(
    const float* __restrict__ x,   // (B, P)
    const fx4* __restrict__ W,     // (P, D/4)
    const fx4* __restrict__ b,     // (P, D/4)
    fx4* __restrict__ out)         // (B, P, D/4)
{
    int idx = blockIdx.x * blockDim.x + threadIdx.x;

    int d4    = idx & (D4 - 1);
    int t     = idx >> 7;          // t = chunk*P + i
    int chunk = t / P_DIM;         // magic-multiply div
    int i     = t - chunk * P_DIM;
    int bt0   = chunk * BT_CHUNK;

    fx4 wv = W[i * D4 + d4];
    fx4 bv = b[i * D4 + d4];

    const float* xp = x + bt0 * P_DIM + i;
    fx4* op = out + (long)(bt0 * P_DIM + i) * D4 + d4;

#pragma unroll
    for (int k = 0; k < BT_CHUNK; ++k) {
        float xv = xp[k * P_DIM];          // wave-uniform broadcast load
        fx4 o;
        o.x = fmaf(xv, wv.x, bv.x);
        o.y = fmaf(xv, wv.y, bv.y);
        o.z = fmaf(xv, wv.z, bv.z);
        o.w = fmaf(xv, wv.w, bv.w);
        __builtin_nontemporal_store(o, &op[(long)k * P_DIM * D4]);
    }
}

extern "C" void kernel_launch(void* const* d_in, const int* in_sizes, int n_in,
                              void* d_out, int out_size, void* d_ws, size_t ws_size,
                              hipStream_t stream) {
    const float* x = (const float*)d_in[0];
    const fx4*   W = (const fx4*)d_in[1];
    const fx4*   b = (const fx4*)d_in[2];
    fx4* out = (fx4*)d_out;

    const int threads = 256;
    const int blocks  = N_THREADS / threads;   // 4000
    FeatureExpander_49185965473877_kernel<<<blocks, threads, 0, stream>>>(x, W, b, out);
}

// Round 4
// 264.480 us; speedup vs baseline: 1.0739x; 1.0108x over previous
//
#include <hip/hip_runtime.h>
#include <hip/hip_bf16.h>

// out[bt, i, d] = x[bt, i] * W[i, d] + b[i, d]
// B=64, P=2000, D=512, all float32.
//
// R4: R3 structure (thread owns (i,d4), loops over bt -> W/b in registers,
// read traffic ~34MB compulsory) with two changes:
//  - PLAIN stores, not nontemporal: the harness's own fill kernel proves
//    plain write streams hit 6.35 TB/s; nt bypasses L2 and regressed us,
//    and W/b are only read 4x anyway (nothing to protect).
//  - unroll 2 instead of 16: a full unroll issued 16 stores 4MB apart
//    back-to-back, keeping 16 open DRAM-page streams per wave -> row
//    thrash. Two outstanding streams per wave is enough ILP.

typedef float fx4 __attribute__((ext_vector_type(4)));

#define B_DIM 64
#define P_DIM 2000
#define D4 128                 // D/4 float4s per row
#define BT_CHUNK 16
#define N_CHUNK (B_DIM / BT_CHUNK)            // 4
#define N_THREADS (N_CHUNK * P_DIM * D4)      // 1,024,000

__global__ __launch_bounds__(256) void FeatureExpander_49185965473877_kernel(
    const float* __restrict__ x,   // (B, P)
    const fx4* __restrict__ W,     // (P, D/4)
    const fx4* __restrict__ b,     // (P, D/4)
    fx4* __restrict__ out)         // (B, P, D/4)
{
    int idx = blockIdx.x * blockDim.x + threadIdx.x;

    int d4    = idx & (D4 - 1);
    int t     = idx >> 7;          // t = chunk*P + i
    int chunk = t / P_DIM;         // magic-multiply div
    int i     = t - chunk * P_DIM;
    int bt0   = chunk * BT_CHUNK;

    fx4 wv = W[i * D4 + d4];
    fx4 bv = b[i * D4 + d4];

    const float* xp = x + bt0 * P_DIM + i;
    fx4* op = out + (long)(bt0 * P_DIM + i) * D4 + d4;

#pragma unroll 2
    for (int k = 0; k < BT_CHUNK; ++k) {
        float xv = xp[k * P_DIM];          // wave-uniform broadcast load
        fx4 o;
        o.x = fmaf(xv, wv.x, bv.x);
        o.y = fmaf(xv, wv.y, bv.y);
        o.z = fmaf(xv, wv.z, bv.z);
        o.w = fmaf(xv, wv.w, bv.w);
        op[(long)k * P_DIM * D4] = o;
    }
}

extern "C" void kernel_launch(void* const* d_in, const int* in_sizes, int n_in,
                              void* d_out, int out_size, void* d_ws, size_t ws_size,
                              hipStream_t stream) {
    const float* x = (const float*)d_in[0];
    const fx4*   W = (const fx4*)d_in[1];
    const fx4*   b = (const fx4*)d_in[2];
    fx4* out = (fx4*)d_out;

    const int threads = 256;
    const int blocks  = N_THREADS / threads;   // 4000
    FeatureExpander_49185965473877_kernel<<<blocks, threads, 0, stream>>>(x, W, b, out);
}